// Round 1
// baseline (5141.091 us; speedup 1.0000x reference)
//
#include <hip/hip_runtime.h>
#include <hip/hip_bf16.h>
#include <stdint.h>

typedef unsigned short u16;

#define NB  32
#define NT  4096
#define NDZ 128
#define NG  384   // 3*DZ
#define NIN 192   // IN_DIM

// ---------- helpers ----------
__device__ __forceinline__ float rlane(float v, int k) {
  return __int_as_float(__builtin_amdgcn_readlane(__float_as_int(v), k));
}
__device__ __forceinline__ float fast_rcp(float x) { return __builtin_amdgcn_rcpf(x); }
__device__ __forceinline__ float sigmoid_f(float x) { return fast_rcp(1.f + __expf(-x)); }
__device__ __forceinline__ float tanh_f(float x) {
  return 1.f - 2.f * fast_rcp(1.f + __expf(2.f * x));
}
__device__ __forceinline__ u16 f2bf(float f) {
  unsigned u = __float_as_uint(f);
  return (u16)((u + 0x7fffu + ((u >> 16) & 1u)) >> 16);
}
__device__ __forceinline__ float bf2f(u16 u) { return __uint_as_float((unsigned)u << 16); }

// LDS-only barrier: does NOT drain vmcnt (unlike __syncthreads, which hipcc
// lowers to s_waitcnt vmcnt(0) lgkmcnt(0) + s_barrier). The scan loop's
// per-step gi prefetch loads + traj store would otherwise be force-drained
// at every barrier, exposing ~600-800 cyc of HBM latency per step.
// Cross-wave data is LDS-only (zbuf, P) -> lgkmcnt(0) is the exact fence.
__device__ __forceinline__ void bar_lds() {
  asm volatile("s_waitcnt lgkmcnt(0)\n\ts_barrier" ::: "memory");
}

// gi workspace: bf16 validated in R3 (absmax 3.9e-3 << 5.9e-2); f32 if ws allows
__device__ __forceinline__ float giload(const float* p) { return *p; }
__device__ __forceinline__ float giload(const u16* p)   { return bf2f(*p); }
__device__ __forceinline__ void store8(float* p, const float* v) {
  float4 a = {v[0], v[1], v[2], v[3]}, b = {v[4], v[5], v[6], v[7]};
  *(float4*)p = a; *(float4*)(p + 4) = b;
}
__device__ __forceinline__ void store8(u16* p, const float* v) {
  uint4 o;
  o.x = (unsigned)f2bf(v[0]) | ((unsigned)f2bf(v[1]) << 16);
  o.y = (unsigned)f2bf(v[2]) | ((unsigned)f2bf(v[3]) << 16);
  o.z = (unsigned)f2bf(v[4]) | ((unsigned)f2bf(v[5]) << 16);
  o.w = (unsigned)f2bf(v[6]) | ((unsigned)f2bf(v[7]) << 16);
  *(uint4*)p = o;
}

// ---------- Phase 1: gi = x @ W_ih^T + b_ih (unchanged from R3) ----------
#define GM 128
#define GN 128
#define LDSS 132

template <typename GT>
__global__ __launch_bounds__(256) void gemm_gi(
    const float* __restrict__ Y, const float* __restrict__ M,
    const float* __restrict__ H, const float* __restrict__ Wih,
    const float* __restrict__ bih, GT* __restrict__ gi)
{
  __shared__ float As[32 * LDSS];
  __shared__ float Bs[32 * LDSS];
  const int tid = threadIdx.x;
  const size_t m0 = (size_t)blockIdx.x * GM;
  const int n0 = blockIdx.y * GN;
  const int tm = tid & 15;
  const int tn = tid >> 4;

  float acc[8][8];
#pragma unroll
  for (int i = 0; i < 8; ++i)
#pragma unroll
    for (int j = 0; j < 8; ++j) acc[i][j] = 0.f;

#pragma unroll
  for (int kc = 0; kc < 6; ++kc) {
    const float* src; int stride; int off;
    if (kc == 0)      { src = Y; stride = 32;  off = 0; }
    else if (kc == 1) { src = M; stride = 32;  off = 0; }
    else              { src = H; stride = 128; off = (kc - 2) * 32; }
#pragma unroll
    for (int it = 0; it < 4; ++it) {
      int x = tid + it * 256;
      int row = x >> 3, q = x & 7;
      float4 v = *(const float4*)(src + (m0 + (size_t)row) * stride + off + q * 4);
      As[(q * 4 + 0) * LDSS + row] = v.x;
      As[(q * 4 + 1) * LDSS + row] = v.y;
      As[(q * 4 + 2) * LDSS + row] = v.z;
      As[(q * 4 + 3) * LDSS + row] = v.w;
    }
#pragma unroll
    for (int it = 0; it < 4; ++it) {
      int x = tid + it * 256;
      int g = x >> 3, q = x & 7;
      float4 v = *(const float4*)(Wih + (size_t)(n0 + g) * NIN + kc * 32 + q * 4);
      Bs[(q * 4 + 0) * LDSS + g] = v.x;
      Bs[(q * 4 + 1) * LDSS + g] = v.y;
      Bs[(q * 4 + 2) * LDSS + g] = v.z;
      Bs[(q * 4 + 3) * LDSS + g] = v.w;
    }
    __syncthreads();
#pragma unroll
    for (int kk = 0; kk < 32; ++kk) {
      float4 a0 = *(const float4*)&As[kk * LDSS + tm * 8];
      float4 a1 = *(const float4*)&As[kk * LDSS + tm * 8 + 4];
      float4 b0 = *(const float4*)&Bs[kk * LDSS + tn * 8];
      float4 b1 = *(const float4*)&Bs[kk * LDSS + tn * 8 + 4];
      float av[8] = {a0.x, a0.y, a0.z, a0.w, a1.x, a1.y, a1.z, a1.w};
      float bv[8] = {b0.x, b0.y, b0.z, b0.w, b1.x, b1.y, b1.z, b1.w};
#pragma unroll
      for (int i = 0; i < 8; ++i)
#pragma unroll
        for (int j = 0; j < 8; ++j)
          acc[i][j] = __builtin_fmaf(av[i], bv[j], acc[i][j]);
    }
    __syncthreads();
  }
  float bv[8];
#pragma unroll
  for (int j = 0; j < 8; ++j) bv[j] = bih[n0 + tn * 8 + j];
#pragma unroll
  for (int i = 0; i < 8; ++i) {
    size_t row = m0 + (size_t)(tm * 8 + i);
    GT* o = gi + row * NG + n0 + tn * 8;
    float v[8];
#pragma unroll
    for (int j = 0; j < 8; ++j) v[j] = acc[i][j] + bv[j];
    store8(o, v);
  }
}

// ---------- Phase 2: scan, 512 thr (8 waves), fine K-split ----------
// Wave w owns k-slice [16w,16w+16). Lane owns rows lane+64j (j=0..5) at that
// slice: 96 weight VGPRs as 3 row-pair float2 x 16 k (pk_fma-friendly).
// Step: [gate thr: z_d -> zbuf] B1 [all: matvec partials -> P] B2
//       [gate thr: reduce 8 partials/row, gates, z update, traj store]
// Barriers are LDS-only (bar_lds): vmcnt NOT drained, so the t+2 gi
// prefetch and traj store stay in flight across steps.
#define KS 16

template <typename GT>
__global__ __launch_bounds__(512, 2) void scan_k(
    const float* __restrict__ zinit, const float* __restrict__ tdyn,
    const int* __restrict__ lens, const float* __restrict__ Whh,
    const float* __restrict__ bhh, const float* __restrict__ lgam,
    const GT* __restrict__ gi, float* __restrict__ out)
{
  const int b = blockIdx.x;
  const int tid = threadIdx.x;   // 0..511
  const int lane = tid & 63;
  const int w = tid >> 6;        // wave 0..7
  const int k0 = w * KS;

  __shared__ float P[8][NG];     // 12 KB partials
  __shared__ float zbuf[NDZ];    // z_d broadcast

  // weights: row pairs (lane+128p, lane+128p+64), k in [k0,k0+16)
  float2 wp[3][KS];
#pragma unroll
  for (int p = 0; p < 3; ++p) {
    const float* r0 = Whh + (size_t)(lane + 128 * p) * NDZ + k0;
    const float* r1 = Whh + (size_t)(lane + 128 * p + 64) * NDZ + k0;
    float4 a[4], c[4];
#pragma unroll
    for (int q = 0; q < 4; ++q) { a[q] = ((const float4*)r0)[q]; c[q] = ((const float4*)r1)[q]; }
    const float* af = (const float*)a;
    const float* cf = (const float*)c;
#pragma unroll
    for (int k = 0; k < KS; ++k) { wp[p][k].x = af[k]; wp[p][k].y = cf[k]; }
  }

  const int len = lens[b];
  const bool gate = (tid < NDZ);
  const int j = tid;  // z-element for gate threads

  float zc = 0.f, gam = 0.f, br = 0.f, bu = 0.f, bn = 0.f;
  float t_prev = 0.f;
  const float* tp = tdyn + (size_t)b * NT;
  const GT* gb = gi + (size_t)b * NT * NG;
  float* traj = out + (size_t)NB * NDZ + (size_t)b * NT * NDZ;

  float ptk[2], pgr[2], pgu[2], pgn[2];
  if (gate) {
    zc = zinit[b * NDZ + j];
    const float lg = lgam[j];
    gam = (lg > 15.f) ? lg : __logf(1.f + __expf(lg));
    br = bhh[j]; bu = bhh[NDZ + j]; bn = bhh[2 * NDZ + j];
    t_prev = tp[0];
#pragma unroll
    for (int s2 = 0; s2 < 2; ++s2) {
      ptk[s2] = tp[s2];
      pgr[s2] = giload(gb + s2 * NG + j);
      pgu[s2] = giload(gb + s2 * NG + NDZ + j);
      pgn[s2] = giload(gb + s2 * NG + 2 * NDZ + j);
    }
  }

  for (int t = 0; t < NT; ++t) {
    const int s = t & 1;
    float zd = 0.f, tk = 0.f;
    if (gate) {
      tk = ptk[s];
      float dt = fmaxf(tk - t_prev, 0.f);
      zd = zc * __expf(-gam * dt);
      zbuf[j] = zd;
      t_prev = tk;
    }
    bar_lds();  // B1: zbuf published (LDS fence only; vmcnt stays in flight)

    const bool active = (t < len);  // block-uniform
    if (active) {
      const float vz = zbuf[k0 + (lane & 15)];  // lane i<16 holds z[k0+i]
      float2 a0 = {0.f, 0.f}, a1 = {0.f, 0.f}, a2 = {0.f, 0.f};
#pragma unroll
      for (int k = 0; k < KS; ++k) {
        const float zk = rlane(vz, k);
        a0.x = __builtin_fmaf(wp[0][k].x, zk, a0.x);
        a0.y = __builtin_fmaf(wp[0][k].y, zk, a0.y);
        a1.x = __builtin_fmaf(wp[1][k].x, zk, a1.x);
        a1.y = __builtin_fmaf(wp[1][k].y, zk, a1.y);
        a2.x = __builtin_fmaf(wp[2][k].x, zk, a2.x);
        a2.y = __builtin_fmaf(wp[2][k].y, zk, a2.y);
      }
      P[w][lane]       = a0.x;  P[w][lane + 64]  = a0.y;
      P[w][lane + 128] = a1.x;  P[w][lane + 192] = a1.y;
      P[w][lane + 256] = a2.x;  P[w][lane + 320] = a2.y;
    }
    bar_lds();  // B2: partials published

    if (gate) {
      if (active) {
        float sr0 = P[0][j] + P[1][j], sr1 = P[2][j] + P[3][j];
        float sr2 = P[4][j] + P[5][j], sr3 = P[6][j] + P[7][j];
        float su0 = P[0][NDZ + j] + P[1][NDZ + j], su1 = P[2][NDZ + j] + P[3][NDZ + j];
        float su2 = P[4][NDZ + j] + P[5][NDZ + j], su3 = P[6][NDZ + j] + P[7][NDZ + j];
        float sn0 = P[0][2 * NDZ + j] + P[1][2 * NDZ + j], sn1 = P[2][2 * NDZ + j] + P[3][2 * NDZ + j];
        float sn2 = P[4][2 * NDZ + j] + P[5][2 * NDZ + j], sn3 = P[6][2 * NDZ + j] + P[7][2 * NDZ + j];
        const float sr = (sr0 + sr1) + (sr2 + sr3);
        const float su = (su0 + su1) + (su2 + su3);
        const float sn = (sn0 + sn1) + (sn2 + sn3);
        const float r = sigmoid_f(sr + br + pgr[s]);
        const float u = sigmoid_f(su + bu + pgu[s]);
        const float n = tanh_f(__builtin_fmaf(r, sn + bn, pgn[s]));
        zc = (1.f - u) * n + u * zd;
      } else {
        zc = zd;
      }
      traj[(size_t)t * NDZ + j] = zc;
      const int t2 = t + 2;
      if (t2 < NT) {
        const GT* g2 = gb + (size_t)t2 * NG;
        ptk[s] = tp[t2];
        pgr[s] = giload(g2 + j);
        pgu[s] = giload(g2 + NDZ + j);
        pgn[s] = giload(g2 + 2 * NDZ + j);
      }
    }
  }
  if (gate) out[b * NDZ + j] = zc;  // z_final
}

extern "C" void kernel_launch(void* const* d_in, const int* in_sizes, int n_in,
                              void* d_out, int out_size, void* d_ws, size_t ws_size,
                              hipStream_t stream) {
  const float* z0   = (const float*)d_in[0];
  const float* tdyn = (const float*)d_in[1];
  const float* Y    = (const float*)d_in[2];
  const float* M    = (const float*)d_in[3];
  const int*   lens = (const int*)d_in[4];
  const float* H    = (const float*)d_in[5];
  const float* Wih  = (const float*)d_in[6];
  const float* bih  = (const float*)d_in[7];
  const float* Whh  = (const float*)d_in[8];
  const float* bhh  = (const float*)d_in[9];
  const float* lgam = (const float*)d_in[10];
  float* out = (float*)d_out;  // f32: [B*DZ] z_final, then [B*T*DZ] Z_traj

  const size_t needF32 = (size_t)NB * NT * NG * sizeof(float);  // 201.3 MB
  dim3 ggrid((NB * NT) / GM, NG / GN);
  if (ws_size >= needF32) {
    float* gi = (float*)d_ws;
    gemm_gi<float><<<ggrid, 256, 0, stream>>>(Y, M, H, Wih, bih, gi);
    scan_k<float><<<dim3(NB), 512, 0, stream>>>(z0, tdyn, lens, Whh, bhh, lgam, gi, out);
  } else {
    u16* gi = (u16*)d_ws;  // bf16 gi (validated: R3 absmax 3.9e-3)
    gemm_gi<u16><<<ggrid, 256, 0, stream>>>(Y, M, H, Wih, bih, gi);
    scan_k<u16><<<dim3(NB), 512, 0, stream>>>(z0, tdyn, lens, Whh, bhh, lgam, gi, out);
  }
}

// Round 2
// 3479.902 us; speedup vs baseline: 1.4774x; 1.4774x over previous
//
#include <hip/hip_runtime.h>
#include <hip/hip_bf16.h>
#include <stdint.h>

typedef unsigned short u16;

#define NB  32
#define NT  4096
#define NDZ 128
#define NG  384   // 3*DZ
#define NIN 192   // IN_DIM

// ---------- helpers ----------
__device__ __forceinline__ float rlane(float v, int k) {
  return __int_as_float(__builtin_amdgcn_readlane(__float_as_int(v), k));
}
__device__ __forceinline__ float fast_rcp(float x) { return __builtin_amdgcn_rcpf(x); }
__device__ __forceinline__ float sigmoid_f(float x) { return fast_rcp(1.f + __expf(-x)); }
__device__ __forceinline__ float tanh_f(float x) {
  return 1.f - 2.f * fast_rcp(1.f + __expf(2.f * x));
}
__device__ __forceinline__ u16 f2bf(float f) {
  unsigned u = __float_as_uint(f);
  return (u16)((u + 0x7fffu + ((u >> 16) & 1u)) >> 16);
}
__device__ __forceinline__ float bf2f(u16 u) { return __uint_as_float((unsigned)u << 16); }

// LDS-only barrier (ds ops drained via lgkmcnt; vmcnt stays in flight so the
// t+2 gi prefetch and traj stores cross barriers without draining).
__device__ __forceinline__ void bar_lds() {
  asm volatile("s_waitcnt lgkmcnt(0)\n\ts_barrier" ::: "memory");
}

// gi workspace: bf16 validated in R3 (absmax 3.9e-3 << 5.9e-2); f32 if ws allows
__device__ __forceinline__ float giload(const float* p) { return *p; }
__device__ __forceinline__ float giload(const u16* p)   { return bf2f(*p); }
__device__ __forceinline__ void store8(float* p, const float* v) {
  float4 a = {v[0], v[1], v[2], v[3]}, b = {v[4], v[5], v[6], v[7]};
  *(float4*)p = a; *(float4*)(p + 4) = b;
}
__device__ __forceinline__ void store8(u16* p, const float* v) {
  uint4 o;
  o.x = (unsigned)f2bf(v[0]) | ((unsigned)f2bf(v[1]) << 16);
  o.y = (unsigned)f2bf(v[2]) | ((unsigned)f2bf(v[3]) << 16);
  o.z = (unsigned)f2bf(v[4]) | ((unsigned)f2bf(v[5]) << 16);
  o.w = (unsigned)f2bf(v[6]) | ((unsigned)f2bf(v[7]) << 16);
  *(uint4*)p = o;
}

// ---------- Phase 1: gi = x @ W_ih^T + b_ih (unchanged) ----------
#define GM 128
#define GN 128
#define LDSS 132

template <typename GT>
__global__ __launch_bounds__(256) void gemm_gi(
    const float* __restrict__ Y, const float* __restrict__ M,
    const float* __restrict__ H, const float* __restrict__ Wih,
    const float* __restrict__ bih, GT* __restrict__ gi)
{
  __shared__ float As[32 * LDSS];
  __shared__ float Bs[32 * LDSS];
  const int tid = threadIdx.x;
  const size_t m0 = (size_t)blockIdx.x * GM;
  const int n0 = blockIdx.y * GN;
  const int tm = tid & 15;
  const int tn = tid >> 4;

  float acc[8][8];
#pragma unroll
  for (int i = 0; i < 8; ++i)
#pragma unroll
    for (int j = 0; j < 8; ++j) acc[i][j] = 0.f;

#pragma unroll
  for (int kc = 0; kc < 6; ++kc) {
    const float* src; int stride; int off;
    if (kc == 0)      { src = Y; stride = 32;  off = 0; }
    else if (kc == 1) { src = M; stride = 32;  off = 0; }
    else              { src = H; stride = 128; off = (kc - 2) * 32; }
#pragma unroll
    for (int it = 0; it < 4; ++it) {
      int x = tid + it * 256;
      int row = x >> 3, q = x & 7;
      float4 v = *(const float4*)(src + (m0 + (size_t)row) * stride + off + q * 4);
      As[(q * 4 + 0) * LDSS + row] = v.x;
      As[(q * 4 + 1) * LDSS + row] = v.y;
      As[(q * 4 + 2) * LDSS + row] = v.z;
      As[(q * 4 + 3) * LDSS + row] = v.w;
    }
#pragma unroll
    for (int it = 0; it < 4; ++it) {
      int x = tid + it * 256;
      int g = x >> 3, q = x & 7;
      float4 v = *(const float4*)(Wih + (size_t)(n0 + g) * NIN + kc * 32 + q * 4);
      Bs[(q * 4 + 0) * LDSS + g] = v.x;
      Bs[(q * 4 + 1) * LDSS + g] = v.y;
      Bs[(q * 4 + 2) * LDSS + g] = v.z;
      Bs[(q * 4 + 3) * LDSS + g] = v.w;
    }
    __syncthreads();
#pragma unroll
    for (int kk = 0; kk < 32; ++kk) {
      float4 a0 = *(const float4*)&As[kk * LDSS + tm * 8];
      float4 a1 = *(const float4*)&As[kk * LDSS + tm * 8 + 4];
      float4 b0 = *(const float4*)&Bs[kk * LDSS + tn * 8];
      float4 b1 = *(const float4*)&Bs[kk * LDSS + tn * 8 + 4];
      float av[8] = {a0.x, a0.y, a0.z, a0.w, a1.x, a1.y, a1.z, a1.w};
      float bv[8] = {b0.x, b0.y, b0.z, b0.w, b1.x, b1.y, b1.z, b1.w};
#pragma unroll
      for (int i = 0; i < 8; ++i)
#pragma unroll
        for (int j = 0; j < 8; ++j)
          acc[i][j] = __builtin_fmaf(av[i], bv[j], acc[i][j]);
    }
    __syncthreads();
  }
  float bv[8];
#pragma unroll
  for (int j = 0; j < 8; ++j) bv[j] = bih[n0 + tn * 8 + j];
#pragma unroll
  for (int i = 0; i < 8; ++i) {
    size_t row = m0 + (size_t)(tm * 8 + i);
    GT* o = gi + row * NG + n0 + tn * 8;
    float v[8];
#pragma unroll
    for (int j = 0; j < 8; ++j) v[j] = acc[i][j] + bv[j];
    store8(o, v);
  }
}

// ---------- Phase 2: scan, ONE barrier per step ----------
// Wave w owns BOTH the K-slice [16w,16w+16) of the matvec AND the gate math
// for elems [16w,16w+16) (lane e <-> elem 16w+e; lanes 16-63 mirror via
// lane&15 so no divergence; only lanes 0-15 store).  z_d for wave w's K-slice
// is therefore produced in its own registers -> no zbuf, no phase A, and
// rlane(zdr,k) broadcasts it with zero LDS traffic.
// P is double-buffered: B(t) writes P[t&1], one barrier, C(t) reads P[t&1];
// B(t+1) writes P[~t&1] so no WAR with laggard readers -> 1 barrier/step.
// Gate reads: 3 gates split over lane groups g=lane>>4 (8 reads each),
// su/sn gathered with two __shfl.
#define KS 16

template <typename GT>
__global__ __launch_bounds__(512, 1) void scan_k(
    const float* __restrict__ zinit, const float* __restrict__ tdyn,
    const int* __restrict__ lens, const float* __restrict__ Whh,
    const float* __restrict__ bhh, const float* __restrict__ lgam,
    const GT* __restrict__ gi, float* __restrict__ out)
{
  const int b = blockIdx.x;
  const int tid = threadIdx.x;   // 0..511
  const int lane = tid & 63;
  const int w = tid >> 6;        // wave 0..7
  const int k0 = w * KS;
  const int e = lane & 15;
  const int j = k0 + e;          // owned elem (mirrored in lanes 16-63)

  __shared__ float P0[8][NG];    // 12 KB
  __shared__ float P1[8][NG];    // 12 KB

  // weights: row pairs (lane+128p, lane+128p+64), k in [k0,k0+16)
  // static indexing only (no pointer-cast repack) so regalloc keeps it in VGPRs
  float2 wp[3][KS];
#pragma unroll
  for (int p = 0; p < 3; ++p) {
    const float4* r0 = (const float4*)(Whh + (size_t)(lane + 128 * p) * NDZ + k0);
    const float4* r1 = (const float4*)(Whh + (size_t)(lane + 128 * p + 64) * NDZ + k0);
#pragma unroll
    for (int q = 0; q < 4; ++q) {
      float4 v0 = r0[q];
      float4 v1 = r1[q];
      wp[p][4 * q + 0].x = v0.x; wp[p][4 * q + 0].y = v1.x;
      wp[p][4 * q + 1].x = v0.y; wp[p][4 * q + 1].y = v1.y;
      wp[p][4 * q + 2].x = v0.z; wp[p][4 * q + 2].y = v1.z;
      wp[p][4 * q + 3].x = v0.w; wp[p][4 * q + 3].y = v1.w;
    }
  }

  const int len = lens[b];
  const float* tp = tdyn + (size_t)b * NT;
  const GT* gb = gi + (size_t)b * NT * NG;
  float* traj = out + (size_t)NB * NDZ + (size_t)b * NT * NDZ;

  // per-elem state (mirrored across lane groups; only lanes 0-15 authoritative)
  float zc = zinit[b * NDZ + j];
  const float lg = lgam[j];
  const float gam = (lg > 15.f) ? lg : __logf(1.f + __expf(lg));
  const float br = bhh[j], bu = bhh[NDZ + j], bn = bhh[2 * NDZ + j];
  float t_prev = tp[0];
  float zdr = zc;                // z_d(0) = z0 (dt0 = 0)

  // gate row for this lane's group: g = lane>>4 in {0,1,2}, lanes 48-63 mirror g=0
  const int gsel = lane >> 4;
  const int g3 = (gsel < 3) ? gsel : 0;
  const int prow = j + 128 * g3;

  // prefetch buffers (manually double-buffered; static names, no runtime index)
  float ptkA = tp[1];
  float ptkB = tp[2];
  float pgrA = giload(gb + j), pguA = giload(gb + NDZ + j), pgnA = giload(gb + 2 * NDZ + j);
  float pgrB = giload(gb + NG + j), pguB = giload(gb + NG + NDZ + j), pgnB = giload(gb + NG + 2 * NDZ + j);

  auto stepf = [&](float (*PB)[NG], float& ptkX, float& pgrX, float& pguX, float& pgnX, int t) {
    const bool active = (t < len);  // block-uniform
    if (active) {
      float2 a0 = {0.f, 0.f}, a1 = {0.f, 0.f}, a2 = {0.f, 0.f};
#pragma unroll
      for (int k = 0; k < KS; ++k) {
        const float zk = rlane(zdr, k);   // z_d[k0+k], produced in-wave last step
        a0.x = __builtin_fmaf(wp[0][k].x, zk, a0.x);
        a0.y = __builtin_fmaf(wp[0][k].y, zk, a0.y);
        a1.x = __builtin_fmaf(wp[1][k].x, zk, a1.x);
        a1.y = __builtin_fmaf(wp[1][k].y, zk, a1.y);
        a2.x = __builtin_fmaf(wp[2][k].x, zk, a2.x);
        a2.y = __builtin_fmaf(wp[2][k].y, zk, a2.y);
      }
      PB[w][lane]       = a0.x;  PB[w][lane + 64]  = a0.y;
      PB[w][lane + 128] = a1.x;  PB[w][lane + 192] = a1.y;
      PB[w][lane + 256] = a2.x;  PB[w][lane + 320] = a2.y;
    }
    bar_lds();  // ONLY barrier of the step: partials published

    const float zd = zdr;
    if (active) {
      // per-lane-group gate sum (8 partials, same tree as before)
      float s0 = PB[0][prow] + PB[1][prow];
      float s1 = PB[2][prow] + PB[3][prow];
      float s2 = PB[4][prow] + PB[5][prow];
      float s3 = PB[6][prow] + PB[7][prow];
      const float sg = (s0 + s1) + (s2 + s3);
      // lane e: sr is own sg (g=0); su from lane e+16, sn from lane e+32
      const float su = __shfl(sg, e + 16, 64);
      const float sn = __shfl(sg, e + 32, 64);
      const float r = sigmoid_f(sg + br + pgrX);
      const float u = sigmoid_f(su + bu + pguX);
      const float n = tanh_f(__builtin_fmaf(r, sn + bn, pgnX));
      zc = (1.f - u) * n + u * zd;
    } else {
      zc = zd;
    }
    if (lane < 16) traj[(size_t)t * NDZ + j] = zc;

    // z_d(t+1) = zc * exp(-gam * max(tp[t+1]-tp[t],0)), computed in-wave
    const float tk = ptkX;
    const float dt = fmaxf(tk - t_prev, 0.f);
    zdr = zc * __expf(-gam * dt);
    t_prev = tk;

    // prefetch for step t+2 (clamped; values unused past the end)
    const int t2 = (t + 2 < NT) ? (t + 2) : (NT - 1);
    const int t3 = (t + 3 < NT) ? (t + 3) : (NT - 1);
    ptkX = tp[t3];
    const GT* g2 = gb + (size_t)t2 * NG;
    pgrX = giload(g2 + j);
    pguX = giload(g2 + NDZ + j);
    pgnX = giload(g2 + 2 * NDZ + j);
  };

  for (int t = 0; t < NT; t += 2) {
    stepf(P0, ptkA, pgrA, pguA, pgnA, t);
    stepf(P1, ptkB, pgrB, pguB, pgnB, t + 1);
  }
  if (lane < 16) out[b * NDZ + j] = zc;  // z_final
}

extern "C" void kernel_launch(void* const* d_in, const int* in_sizes, int n_in,
                              void* d_out, int out_size, void* d_ws, size_t ws_size,
                              hipStream_t stream) {
  const float* z0   = (const float*)d_in[0];
  const float* tdyn = (const float*)d_in[1];
  const float* Y    = (const float*)d_in[2];
  const float* M    = (const float*)d_in[3];
  const int*   lens = (const int*)d_in[4];
  const float* H    = (const float*)d_in[5];
  const float* Wih  = (const float*)d_in[6];
  const float* bih  = (const float*)d_in[7];
  const float* Whh  = (const float*)d_in[8];
  const float* bhh  = (const float*)d_in[9];
  const float* lgam = (const float*)d_in[10];
  float* out = (float*)d_out;  // f32: [B*DZ] z_final, then [B*T*DZ] Z_traj

  const size_t needF32 = (size_t)NB * NT * NG * sizeof(float);  // 201.3 MB
  dim3 ggrid((NB * NT) / GM, NG / GN);
  if (ws_size >= needF32) {
    float* gi = (float*)d_ws;
    gemm_gi<float><<<ggrid, 256, 0, stream>>>(Y, M, H, Wih, bih, gi);
    scan_k<float><<<dim3(NB), 512, 0, stream>>>(z0, tdyn, lens, Whh, bhh, lgam, gi, out);
  } else {
    u16* gi = (u16*)d_ws;  // bf16 gi (validated: R3 absmax 3.9e-3)
    gemm_gi<u16><<<ggrid, 256, 0, stream>>>(Y, M, H, Wih, bih, gi);
    scan_k<u16><<<dim3(NB), 512, 0, stream>>>(z0, tdyn, lens, Whh, bhh, lgam, gi, out);
  }
}